// Round 4
// baseline (287.700 us; speedup 1.0000x reference)
//
#include <hip/hip_runtime.h>

#define NN 16384
#define NCB 8
#define DIM 32
#define CB 1024
#define TILE 64            // codebook entries per wave-tile
#define NTILES (CB / TILE) // 16
#define RPB 512            // rows per block (one k)

// Kernel A: csqb[k*CB+c] = ||codebook[k,c]||^2 + rate_bias[k,c]
__global__ __launch_bounds__(256) void vq_csq(const float* __restrict__ cb,
                                              const float* __restrict__ rb,
                                              float* __restrict__ out) {
    int i = blockIdx.x * 256 + threadIdx.x;
    if (i >= NCB * CB) return;
    const float4* c4 = reinterpret_cast<const float4*>(cb + (size_t)i * DIM);
    float s0 = 0.f, s1 = 0.f, s2 = 0.f, s3 = 0.f;
#pragma unroll
    for (int j = 0; j < 8; ++j) {
        float4 v = c4[j];
        s0 = fmaf(v.x, v.x, s0);
        s1 = fmaf(v.y, v.y, s1);
        s2 = fmaf(v.z, v.z, s2);
        s3 = fmaf(v.w, v.w, s3);
    }
    out[i] = ((s0 + s1) + (s2 + s3)) + rb[i];
}

// Fused kernel, wave-specialized. 256 blocks (1/CU), 8 waves each:
//   waves 0-3 (compute): scan 1024 codebook entries for 2 rows/thread from
//     per-wave private double-buffered LDS tiles. Their vmcnt FIFO holds only
//     prefetch loads -> tile-boundary waits never drain stores.
//   waves 4-7 (storers): stream the block's 2 MB of one_hot zeros at write BW.
// One __syncthreads() (per-wave vmcnt(0) + s_barrier) orders zeros before the
// 1.0 / x_hat / index scatter. 2 waves/SIMD: store issue overlaps VALU scan.
__global__ __launch_bounds__(512) void vq_fused(const float* __restrict__ x,
                                                const float* __restrict__ cb,
                                                const float* __restrict__ csqb,
                                                float* __restrict__ xhat,
                                                float* __restrict__ onehot,
                                                float* __restrict__ idxf) {
    __shared__ float4 sm[4][2][TILE * 8];  // 4 compute waves * 2 * 8 KB = 64 KB

    const int tid = threadIdx.x;
    const int w = tid >> 6;
    const int lane = tid & 63;
    const int k = blockIdx.x & (NCB - 1);
    const int n0 = (blockIdx.x >> 3) * RPB;

    if (w >= 4) {
        // ---- storer wave: zero 128 one_hot rows (4 KB each) ----
        const int ws = w - 4;
        float4* oh4 = reinterpret_cast<float4*>(onehot);
        const float4 z4 = make_float4(0.f, 0.f, 0.f, 0.f);
        const int rbase = n0 + ws * 128;
#pragma unroll 4
        for (int r = 0; r < 128; ++r) {
            float4* rp = oh4 + ((size_t)(rbase + r) * NCB + k) * 256;
#pragma unroll
            for (int j = 0; j < 4; ++j) rp[j * 64 + lane] = z4;
        }
        __syncthreads();  // vmcnt(0): zeros in L2 before scatter proceeds
        return;
    }

    // ---- compute wave ----
    const float* cbk = cb + (size_t)k * CB * DIM;
    const float4* cbk4 = reinterpret_cast<const float4*>(cbk);
    const float* cqk = csqb + k * CB;

    const int r0 = n0 + w * 64 + lane;
    const int r1 = r0 + 256;

    // x rows -> registers; ||x||^2 (frozen chain order)
    float4 xa[8], xb[8];
    {
        const float4* p0 =
            reinterpret_cast<const float4*>(x + ((size_t)r0 * NCB + k) * DIM);
        const float4* p1 =
            reinterpret_cast<const float4*>(x + ((size_t)r1 * NCB + k) * DIM);
#pragma unroll
        for (int j = 0; j < 8; ++j) { xa[j] = p0[j]; xb[j] = p1[j]; }
    }
    float xsa, xsb;
    {
        float q0 = 0.f, q1 = 0.f, q2 = 0.f, q3 = 0.f;
#pragma unroll
        for (int j = 0; j < 8; ++j) {
            q0 = fmaf(xa[j].x, xa[j].x, q0);
            q1 = fmaf(xa[j].y, xa[j].y, q1);
            q2 = fmaf(xa[j].z, xa[j].z, q2);
            q3 = fmaf(xa[j].w, xa[j].w, q3);
        }
        xsa = (q0 + q1) + (q2 + q3);
        q0 = q1 = q2 = q3 = 0.f;
#pragma unroll
        for (int j = 0; j < 8; ++j) {
            q0 = fmaf(xb[j].x, xb[j].x, q0);
            q1 = fmaf(xb[j].y, xb[j].y, q1);
            q2 = fmaf(xb[j].z, xb[j].z, q2);
            q3 = fmaf(xb[j].w, xb[j].w, q3);
        }
        xsb = (q0 + q1) + (q2 + q3);
    }

    // prologue: stage tile 0 into this wave's buffer 0
    float4 st[8];
    float cq_cur, cq_nxt = 0.f;
#pragma unroll
    for (int i = 0; i < 8; ++i) st[i] = cbk4[i * 64 + lane];
    cq_cur = cqk[lane];
#pragma unroll
    for (int i = 0; i < 8; ++i) sm[w][0][i * 64 + lane] = st[i];

    float bda = 3.4028235e38f, bdb = 3.4028235e38f;
    int bia = 0, bib = 0;

    for (int t = 0; t < NTILES; ++t) {
        const int b = t & 1;

        // prefetch next tile into registers (only loads in this wave's FIFO)
        if (t < NTILES - 1) {
#pragma unroll
            for (int i = 0; i < 8; ++i)
                st[i] = cbk4[(t + 1) * (TILE * 8) + i * 64 + lane];
            cq_nxt = cqk[(t + 1) * TILE + lane];
        }

        // compute current tile from this wave's LDS (uniform broadcast reads)
        const float4* buf = &sm[w][b][0];
#pragma unroll 2
        for (int c = 0; c < TILE; ++c) {
            const float cqv = __int_as_float(
                __builtin_amdgcn_readlane(__float_as_int(cq_cur), c));
            float4 a0 = buf[c * 8 + 0], a1 = buf[c * 8 + 1];
            float4 a2 = buf[c * 8 + 2], a3 = buf[c * 8 + 3];
            float4 a4 = buf[c * 8 + 4], a5 = buf[c * 8 + 5];
            float4 a6 = buf[c * 8 + 6], a7 = buf[c * 8 + 7];

            // row A (frozen chain order)
            float d0 = 0.f, d1 = 0.f, d2 = 0.f, d3 = 0.f;
            d0 = fmaf(xa[0].x, a0.x, d0); d1 = fmaf(xa[0].y, a0.y, d1);
            d2 = fmaf(xa[0].z, a0.z, d2); d3 = fmaf(xa[0].w, a0.w, d3);
            d0 = fmaf(xa[1].x, a1.x, d0); d1 = fmaf(xa[1].y, a1.y, d1);
            d2 = fmaf(xa[1].z, a1.z, d2); d3 = fmaf(xa[1].w, a1.w, d3);
            d0 = fmaf(xa[2].x, a2.x, d0); d1 = fmaf(xa[2].y, a2.y, d1);
            d2 = fmaf(xa[2].z, a2.z, d2); d3 = fmaf(xa[2].w, a2.w, d3);
            d0 = fmaf(xa[3].x, a3.x, d0); d1 = fmaf(xa[3].y, a3.y, d1);
            d2 = fmaf(xa[3].z, a3.z, d2); d3 = fmaf(xa[3].w, a3.w, d3);
            d0 = fmaf(xa[4].x, a4.x, d0); d1 = fmaf(xa[4].y, a4.y, d1);
            d2 = fmaf(xa[4].z, a4.z, d2); d3 = fmaf(xa[4].w, a4.w, d3);
            d0 = fmaf(xa[5].x, a5.x, d0); d1 = fmaf(xa[5].y, a5.y, d1);
            d2 = fmaf(xa[5].z, a5.z, d2); d3 = fmaf(xa[5].w, a5.w, d3);
            d0 = fmaf(xa[6].x, a6.x, d0); d1 = fmaf(xa[6].y, a6.y, d1);
            d2 = fmaf(xa[6].z, a6.z, d2); d3 = fmaf(xa[6].w, a6.w, d3);
            d0 = fmaf(xa[7].x, a7.x, d0); d1 = fmaf(xa[7].y, a7.y, d1);
            d2 = fmaf(xa[7].z, a7.z, d2); d3 = fmaf(xa[7].w, a7.w, d3);
            {
                const float dot = (d0 + d1) + (d2 + d3);
                const float dist = fmaf(-2.f, dot, xsa + cqv);
                const int cg = t * TILE + c;
                if (dist < bda) { bda = dist; bia = cg; }
            }
            // row B
            d0 = 0.f; d1 = 0.f; d2 = 0.f; d3 = 0.f;
            d0 = fmaf(xb[0].x, a0.x, d0); d1 = fmaf(xb[0].y, a0.y, d1);
            d2 = fmaf(xb[0].z, a0.z, d2); d3 = fmaf(xb[0].w, a0.w, d3);
            d0 = fmaf(xb[1].x, a1.x, d0); d1 = fmaf(xb[1].y, a1.y, d1);
            d2 = fmaf(xb[1].z, a1.z, d2); d3 = fmaf(xb[1].w, a1.w, d3);
            d0 = fmaf(xb[2].x, a2.x, d0); d1 = fmaf(xb[2].y, a2.y, d1);
            d2 = fmaf(xb[2].z, a2.z, d2); d3 = fmaf(xb[2].w, a2.w, d3);
            d0 = fmaf(xb[3].x, a3.x, d0); d1 = fmaf(xb[3].y, a3.y, d1);
            d2 = fmaf(xb[3].z, a3.z, d2); d3 = fmaf(xb[3].w, a3.w, d3);
            d0 = fmaf(xb[4].x, a4.x, d0); d1 = fmaf(xb[4].y, a4.y, d1);
            d2 = fmaf(xb[4].z, a4.z, d2); d3 = fmaf(xb[4].w, a4.w, d3);
            d0 = fmaf(xb[5].x, a5.x, d0); d1 = fmaf(xb[5].y, a5.y, d1);
            d2 = fmaf(xb[5].z, a5.z, d2); d3 = fmaf(xb[5].w, a5.w, d3);
            d0 = fmaf(xb[6].x, a6.x, d0); d1 = fmaf(xb[6].y, a6.y, d1);
            d2 = fmaf(xb[6].z, a6.z, d2); d3 = fmaf(xb[6].w, a6.w, d3);
            d0 = fmaf(xb[7].x, a7.x, d0); d1 = fmaf(xb[7].y, a7.y, d1);
            d2 = fmaf(xb[7].z, a7.z, d2); d3 = fmaf(xb[7].w, a7.w, d3);
            {
                const float dot = (d0 + d1) + (d2 + d3);
                const float dist = fmaf(-2.f, dot, xsb + cqv);
                const int cg = t * TILE + c;
                if (dist < bdb) { bdb = dist; bib = cg; }
            }
        }

        // write staged tile t+1 into the other buffer (same wave -> no barrier)
        if (t < NTILES - 1) {
#pragma unroll
            for (int i = 0; i < 8; ++i) sm[w][b ^ 1][i * 64 + lane] = st[i];
            cq_cur = cq_nxt;
        }
    }

    __syncthreads();  // storer zeros drained; safe to scatter

    // epilogue: index / x_hat / one_hot scatter for both rows
    {
        idxf[(size_t)r0 * NCB + k] = (float)bia;
        const float4* src = cbk4 + (size_t)bia * 8;
        float4* dst =
            reinterpret_cast<float4*>(xhat + ((size_t)r0 * NCB + k) * DIM);
#pragma unroll
        for (int j = 0; j < 8; ++j) dst[j] = src[j];
        onehot[((size_t)r0 * NCB + k) * CB + bia] = 1.0f;
    }
    {
        idxf[(size_t)r1 * NCB + k] = (float)bib;
        const float4* src = cbk4 + (size_t)bib * 8;
        float4* dst =
            reinterpret_cast<float4*>(xhat + ((size_t)r1 * NCB + k) * DIM);
#pragma unroll
        for (int j = 0; j < 8; ++j) dst[j] = src[j];
        onehot[((size_t)r1 * NCB + k) * CB + bib] = 1.0f;
    }
}

extern "C" void kernel_launch(void* const* d_in, const int* in_sizes, int n_in,
                              void* d_out, int out_size, void* d_ws,
                              size_t ws_size, hipStream_t stream) {
    const float* x = (const float*)d_in[0];
    const float* cb = (const float*)d_in[1];
    const float* rb = (const float*)d_in[2];

    float* out = (float*)d_out;
    float* xhat = out;                             // N*NCB*DIM
    float* onehot = out + (size_t)NN * NCB * DIM;  // N*NCB*CB
    float* idxf = onehot + (size_t)NN * NCB * CB;  // N*NCB

    float* csqb = (float*)d_ws;  // NCB*CB floats = 32 KB

    vq_csq<<<(NCB * CB + 255) / 256, 256, 0, stream>>>(cb, rb, csqb);
    vq_fused<<<(NN / RPB) * NCB, 512, 0, stream>>>(x, cb, csqb, xhat, onehot,
                                                   idxf);
}

// Round 5
// 286.757 us; speedup vs baseline: 1.0033x; 1.0033x over previous
//
#include <hip/hip_runtime.h>

#define NN 16384
#define NCB 8
#define DIM 32
#define CB 1024
#define RPB 512  // rows per block (one k)

// Kernel A: csqb[k*CB+c] = ||codebook[k,c]||^2 + rate_bias[k,c]
__global__ __launch_bounds__(256) void vq_csq(const float* __restrict__ cb,
                                              const float* __restrict__ rb,
                                              float* __restrict__ out) {
    int i = blockIdx.x * 256 + threadIdx.x;
    if (i >= NCB * CB) return;
    const float4* c4 = reinterpret_cast<const float4*>(cb + (size_t)i * DIM);
    float s0 = 0.f, s1 = 0.f, s2 = 0.f, s3 = 0.f;
#pragma unroll
    for (int j = 0; j < 8; ++j) {
        float4 v = c4[j];
        s0 = fmaf(v.x, v.x, s0);
        s1 = fmaf(v.y, v.y, s1);
        s2 = fmaf(v.z, v.z, s2);
        s3 = fmaf(v.w, v.w, s3);
    }
    out[i] = ((s0 + s1) + (s2 + s3)) + rb[i];
}

// Fused kernel, scalar-broadcast scan:
//   256 blocks (1/CU) x 1024 threads (16 waves, 4/SIMD).
//   Wave pair p = waves {2p,2p+1} owns rows n0+p*64+lane; wave half h = w&1
//   scans codebook c in [h*512, h*512+512). Codebook entries are wave-uniform
//   -> readfirstlane'd index + const __restrict__ => s_load into SGPRs: no LDS
//   broadcast tax, no VMEM loads in the loop. The vmcnt FIFO holds ONLY the
//   interleaved one_hot zero-stores, so they drain in the background and are
//   waited on exactly once (the final __syncthreads). Halves combine via 4 KB
//   LDS with tie -> lower index (preserves argmin first-occurrence).
__global__ __launch_bounds__(1024) void vq_fused(const float* __restrict__ x,
                                                 const float* __restrict__ cb,
                                                 const float* __restrict__ csqb,
                                                 float* __restrict__ xhat,
                                                 float* __restrict__ onehot,
                                                 float* __restrict__ idxf) {
    __shared__ float pd[RPB];
    __shared__ int pi[RPB];

    const int tid = threadIdx.x;
    const int w = tid >> 6;    // 0..15
    const int lane = tid & 63;
    const int p = w >> 1;      // row-group pair 0..7
    const int h = w & 1;       // codebook half
    const int k = blockIdx.x & (NCB - 1);
    const int n0 = (blockIdx.x >> 3) * RPB;
    const int n = n0 + p * 64 + lane;  // this lane's row

    const float* cbk = cb + (size_t)k * CB * DIM;
    const float4* cbk4 = reinterpret_cast<const float4*>(cbk);
    const float* cqk = csqb + (size_t)k * CB;

    // x row -> registers; ||x||^2 (frozen chain order)
    float4 xv[8];
    {
        const float4* xp =
            reinterpret_cast<const float4*>(x + ((size_t)n * NCB + k) * DIM);
#pragma unroll
        for (int j = 0; j < 8; ++j) xv[j] = xp[j];
    }
    float xsq;
    {
        float q0 = 0.f, q1 = 0.f, q2 = 0.f, q3 = 0.f;
#pragma unroll
        for (int j = 0; j < 8; ++j) {
            q0 = fmaf(xv[j].x, xv[j].x, q0);
            q1 = fmaf(xv[j].y, xv[j].y, q1);
            q2 = fmaf(xv[j].z, xv[j].z, q2);
            q3 = fmaf(xv[j].w, xv[j].w, q3);
        }
        xsq = (q0 + q1) + (q2 + q3);
    }

    float best = 3.4028235e38f;
    int bi = 0;
    const int cbase = h * 512;

    float4* oh4 = reinterpret_cast<float4*>(onehot);
    const float4 z4 = make_float4(0.f, 0.f, 0.f, 0.f);

    for (int t = 0; t < 8; ++t) {
        // zero 4 one_hot rows (wave w owns rows n0+w*32 .. +31); coalesced 1KB
        {
            const int rbase = n0 + w * 32 + t * 4;
#pragma unroll
            for (int rr = 0; rr < 4; ++rr) {
                float4* rp = oh4 + ((size_t)(rbase + rr) * NCB + k) * 256;
#pragma unroll
                for (int s = 0; s < 4; ++s) rp[s * 64 + lane] = z4;
            }
        }

        // scan 64 codebook entries via scalar loads (uniform address)
#pragma unroll 2
        for (int cc = 0; cc < 64; ++cc) {
            const int co = __builtin_amdgcn_readfirstlane(cbase + t * 64 + cc);
            const float4* e = cbk4 + (size_t)co * 8;
            const float4 a0 = e[0], a1 = e[1], a2 = e[2], a3 = e[3];
            const float4 a4 = e[4], a5 = e[5], a6 = e[6], a7 = e[7];
            const float cqv = cqk[co];

            // frozen round-2 chain order
            float d0 = 0.f, d1 = 0.f, d2 = 0.f, d3 = 0.f;
            d0 = fmaf(xv[0].x, a0.x, d0); d1 = fmaf(xv[0].y, a0.y, d1);
            d2 = fmaf(xv[0].z, a0.z, d2); d3 = fmaf(xv[0].w, a0.w, d3);
            d0 = fmaf(xv[1].x, a1.x, d0); d1 = fmaf(xv[1].y, a1.y, d1);
            d2 = fmaf(xv[1].z, a1.z, d2); d3 = fmaf(xv[1].w, a1.w, d3);
            d0 = fmaf(xv[2].x, a2.x, d0); d1 = fmaf(xv[2].y, a2.y, d1);
            d2 = fmaf(xv[2].z, a2.z, d2); d3 = fmaf(xv[2].w, a2.w, d3);
            d0 = fmaf(xv[3].x, a3.x, d0); d1 = fmaf(xv[3].y, a3.y, d1);
            d2 = fmaf(xv[3].z, a3.z, d2); d3 = fmaf(xv[3].w, a3.w, d3);
            d0 = fmaf(xv[4].x, a4.x, d0); d1 = fmaf(xv[4].y, a4.y, d1);
            d2 = fmaf(xv[4].z, a4.z, d2); d3 = fmaf(xv[4].w, a4.w, d3);
            d0 = fmaf(xv[5].x, a5.x, d0); d1 = fmaf(xv[5].y, a5.y, d1);
            d2 = fmaf(xv[5].z, a5.z, d2); d3 = fmaf(xv[5].w, a5.w, d3);
            d0 = fmaf(xv[6].x, a6.x, d0); d1 = fmaf(xv[6].y, a6.y, d1);
            d2 = fmaf(xv[6].z, a6.z, d2); d3 = fmaf(xv[6].w, a6.w, d3);
            d0 = fmaf(xv[7].x, a7.x, d0); d1 = fmaf(xv[7].y, a7.y, d1);
            d2 = fmaf(xv[7].z, a7.z, d2); d3 = fmaf(xv[7].w, a7.w, d3);

            const float dot = (d0 + d1) + (d2 + d3);
            const float dist = fmaf(-2.f, dot, xsq + cqv);
            if (dist < best) {  // strict <: first occurrence within half
                best = dist;
                bi = co;
            }
        }
    }

    // publish odd-half partials
    if (h == 1) {
        pd[p * 64 + lane] = best;
        pi[p * 64 + lane] = bi;
    }
    __syncthreads();  // drains all zero-stores (vmcnt(0)) + publishes partials

    if (h == 0) {
        const float od = pd[p * 64 + lane];
        const int oi = pi[p * 64 + lane];
        if (od < best || (od == best && oi < bi)) {  // tie -> lower index
            best = od;
            bi = oi;
        }
        // epilogue: index / x_hat / one_hot scatter
        idxf[(size_t)n * NCB + k] = (float)bi;
        const float4* src = cbk4 + (size_t)bi * 8;
        float4* dst =
            reinterpret_cast<float4*>(xhat + ((size_t)n * NCB + k) * DIM);
#pragma unroll
        for (int j = 0; j < 8; ++j) dst[j] = src[j];
        onehot[((size_t)n * NCB + k) * CB + bi] = 1.0f;
    }
}

extern "C" void kernel_launch(void* const* d_in, const int* in_sizes, int n_in,
                              void* d_out, int out_size, void* d_ws,
                              size_t ws_size, hipStream_t stream) {
    const float* x = (const float*)d_in[0];
    const float* cb = (const float*)d_in[1];
    const float* rb = (const float*)d_in[2];

    float* out = (float*)d_out;
    float* xhat = out;                             // N*NCB*DIM
    float* onehot = out + (size_t)NN * NCB * DIM;  // N*NCB*CB
    float* idxf = onehot + (size_t)NN * NCB * CB;  // N*NCB

    float* csqb = (float*)d_ws;  // NCB*CB floats = 32 KB

    vq_csq<<<(NCB * CB + 255) / 256, 256, 0, stream>>>(cb, rb, csqb);
    vq_fused<<<(NN / RPB) * NCB, 1024, 0, stream>>>(x, cb, csqb, xhat, onehot,
                                                    idxf);
}